// Round 9
// baseline (19.200 us; speedup 1.0000x reference)
//
#include <hip/hip_runtime.h>

#define BLOCK 256
#define TPB 4            // true boxes (columns) per thread
#define CHUNK 128        // pred boxes per block (staged in LDS)
#define WAVES (BLOCK / 64)

__global__ void init_out(float* __restrict__ out, int M) {
    int i = blockIdx.x * blockDim.x + threadIdx.x;
    if (i < M) out[i] = 1.0f;    // atomicMin identity; losses are in [0,1]
}

__global__ __launch_bounds__(BLOCK) void iou_fused(
    const float* __restrict__ pred,   // [N,4] raw
    const float* __restrict__ trub,   // [M,4] raw
    float* __restrict__ out,          // [M], pre-set to 1.0f by init_out
    int N, int M)
{
    __shared__ float2 sp[CHUNK];      // fixed pred corners (fast path)
    __shared__ float4 sbox[CHUNK];    // fixed pred box (generic path)
    __shared__ float  sarea[CHUNK];   // pred areas (generic path)
    __shared__ int    sbadw[WAVES];   // per-wave "not unit box" flags

    const int tid = threadIdx.x;
    const int n0  = blockIdx.y * CHUNK;

    // ---- cooperative load+fix of this block's CHUNK preds ----
    bool bad = false;
    if (tid < CHUNK) {
        int k = n0 + tid; if (k >= N) k = N - 1;   // clamp: duplicate, harmless for max
        float4 b = reinterpret_cast<const float4*>(pred)[k];
        float x1 = fminf(b.x, b.z), y1 = fminf(b.y, b.w);
        float x2 = fmaxf(b.x, b.z), y2 = fmaxf(b.y, b.w);
        bad = (x2 > x1 + 1.0f) || (y2 > y1 + 1.0f);   // unit-box property check
        x2 = fmaxf(x2, x1 + 1.0f); y2 = fmaxf(y2, y1 + 1.0f);  // EPS = 1.0
        sp[tid]    = make_float2(x1, y1);
        sbox[tid]  = make_float4(x1, y1, x2, y2);
        sarea[tid] = (x2 - x1) * (y2 - y1);
    }

    // ---- per-thread load+fix of TPB true boxes (registers) ----
    const int jbase = blockIdx.x * (BLOCK * TPB) + tid;
    float tx[TPB], ty[TPB], X2[TPB], Y2[TPB], TA[TPB];
#pragma unroll
    for (int t = 0; t < TPB; ++t) {
        int j = jbase + t * BLOCK; if (j >= M) j = M - 1;
        float4 b = reinterpret_cast<const float4*>(trub)[j];
        float x1 = fminf(b.x, b.z), y1 = fminf(b.y, b.w);
        float x2 = fmaxf(b.x, b.z), y2 = fmaxf(b.y, b.w);
        bad = bad || (x2 > x1 + 1.0f) || (y2 > y1 + 1.0f);
        x2 = fmaxf(x2, x1 + 1.0f); y2 = fmaxf(y2, y1 + 1.0f);
        tx[t] = x1; ty[t] = y1; X2[t] = x2; Y2[t] = y2;
        TA[t] = (x2 - x1) * (y2 - y1);
    }

    // ---- block-uniform fast/generic decision: per-wave vote, one barrier ----
    int anybad = __any(bad) ? 1 : 0;
    if ((tid & 63) == 0) sbadw[tid >> 6] = anybad;
    __syncthreads();
    int blkbad = 0;
#pragma unroll
    for (int w = 0; w < WAVES; ++w) blkbad |= sbadw[w];

    float best[TPB];
#pragma unroll
    for (int t = 0; t < TPB; ++t) best[t] = 0.0f;

    if (!blkbad) {
        // ---- fast path: all boxes exactly 1x1 -> track max INTERSECTION ----
#pragma unroll
        for (int k = 0; k < CHUNK; ++k) {
            float2 p = sp[k];                      // LDS broadcast (same addr, no conflict)
#pragma unroll
            for (int t = 0; t < TPB; ++t) {
                float wx = 1.0f - fabsf(p.x - tx[t]);               // may be < 0
                float hy = fmaxf(1.0f - fabsf(p.y - ty[t]), 0.0f);  // clamped
                best[t] = fmaxf(best[t], wx * hy);  // wx<0 => product<=0, discarded
            }
        }
        // intersection -> IoU once per column: IoU = i / (2 - i), 2-i in [1,2]
#pragma unroll
        for (int t = 0; t < TPB; ++t)
            best[t] = best[t] * __builtin_amdgcn_rcpf(2.0f - best[t]);
    } else {
        // ---- generic path: full IoU from staged fixed boxes ----
#pragma unroll 4
        for (int k = 0; k < CHUNK; ++k) {
            float4 p  = sbox[k];
            float  pa = sarea[k];
#pragma unroll
            for (int t = 0; t < TPB; ++t) {
                float lx = fmaxf(p.x, tx[t]);
                float ly = fmaxf(p.y, ty[t]);
                float rx = fminf(p.z, X2[t]);
                float ry = fminf(p.w, Y2[t]);
                float w  = fmaxf(rx - lx, 0.0f);
                float h  = fmaxf(ry - ly, 0.0f);
                float inter = w * h;
                float uni   = (pa + TA[t]) - inter;   // >= 1 (EPS forces dims >= 1)
                best[t] = fmaxf(best[t], inter * __builtin_amdgcn_rcpf(uni));
            }
        }
    }

    // ---- combine across pred-splits: atomic min of loss (int bits, all >= 0) ----
#pragma unroll
    for (int t = 0; t < TPB; ++t) {
        int j = jbase + t * BLOCK;
        if (j < M) {
            float loss = 1.0f - best[t];
            atomicMin(reinterpret_cast<int*>(out) + j, __float_as_int(loss));
        }
    }
}

extern "C" void kernel_launch(void* const* d_in, const int* in_sizes, int n_in,
                              void* d_out, int out_size, void* d_ws, size_t ws_size,
                              hipStream_t stream) {
    const float* pred = (const float*)d_in[0];
    const float* trub = (const float*)d_in[1];
    float* out = (float*)d_out;
    const int N = in_sizes[0] / 4;
    const int M = in_sizes[1] / 4;

    init_out<<<(M + BLOCK - 1) / BLOCK, BLOCK, 0, stream>>>(out, M);

    dim3 grid((M + BLOCK * TPB - 1) / (BLOCK * TPB),   // 8  column-groups
              (N + CHUNK - 1) / CHUNK);                // 64 pred-chunks
    iou_fused<<<grid, BLOCK, 0, stream>>>(pred, trub, out, N, M);
}